// Round 15
// baseline (504.085 us; speedup 1.0000x reference)
//
#include <hip/hip_runtime.h>
#include <math.h>

#define N_NODES 8192
#define N_FEAT  256
#define N_EDGES 131072
#define N_DIR   (2*N_EDGES)
#define MAXDEG  128    // slot-table width; in-degree is Poisson(32), P(>=128)~0
#define ACT_CAP 24576  // LDS capacity for residual active pairs

typedef unsigned int u32x4 __attribute__((ext_vector_type(4)));

// ---------- helpers ----------

// directed edge k: s = ei[k]; d = ei[k<E ? k+E : k-E]
__device__ __forceinline__ void edge_sd(const int* __restrict__ ei, int k, int& s, int& d){
  s = ei[k];
  d = (k < N_EDGES) ? ei[k + N_EDGES] : ei[k - N_EDGES];
}

// ---------- kernels ----------

// init meta (cnt|deg|np -> 0), Lg = identity, and zero X_new (8 MB)
__global__ void k_start(int* __restrict__ meta, int nmeta, int* __restrict__ Lg,
                        u32x4* __restrict__ xn4, int nx4){
  int i = blockIdx.x * blockDim.x + threadIdx.x;
  if (i < nmeta) meta[i] = 0;
  if (i < N_NODES) Lg[i] = i;
  u32x4 z = (u32x4)(0u);
  int stride = gridDim.x * blockDim.x;
  for (int k = i; k < nx4; k += stride) __builtin_nontemporal_store(z, &xn4[k]);
}

// p1[i] = dot(x[i], w[:256]); p2[i] = dot(x[i], w[256:])  (f64 accumulate)
__global__ void k_proj(const float* __restrict__ x, const float* __restrict__ w,
                       float* __restrict__ p1, float* __restrict__ p2){
  int i = blockIdx.x;
  int t = threadIdx.x;                  // 256 threads
  float v = x[(size_t)i * N_FEAT + t];
  double a = (double)v * (double)w[t];
  double b = (double)v * (double)w[N_FEAT + t];
  for (int off = 32; off; off >>= 1){
    a += __shfl_down(a, off);
    b += __shfl_down(b, off);
  }
  __shared__ double sa[4], sb[4];
  int wid = t >> 6, lane = t & 63;
  if (lane == 0){ sa[wid] = a; sb[wid] = b; }
  __syncthreads();
  if (t == 0){
    p1[i] = (float)(sa[0] + sa[1] + sa[2] + sa[3]);
    p2[i] = (float)(sb[0] + sb[1] + sb[2] + sb[3]);
  }
}

// e per directed edge; (src,e) slot record by destination; contract degree;
// compacted contract pairs; free CC round 1 (Lg==identity -> atomicMin(hi,lo))
__global__ void k_edges(const int* __restrict__ ei, const float* __restrict__ p1,
                        const float* __restrict__ p2, const float* __restrict__ lb,
                        int* __restrict__ cnt, int* __restrict__ deg,
                        int* __restrict__ Lg, uint2* __restrict__ edata,
                        unsigned int* __restrict__ pairs, int* __restrict__ np){
  int k = blockIdx.x * blockDim.x + threadIdx.x;
  int s, d; edge_sd(ei, k, s, d);
  bool selfe = (s == d);
  float e = 0.0f;
  if (!selfe){
    float z = p1[s] + p2[d] + lb[0];
    e = tanhf(z);
    int slot = atomicAdd(&cnt[d], 1);
    uint2 v; v.x = (unsigned int)s; v.y = __float_as_uint(e);
    edata[(size_t)d * MAXDEG + slot] = v;
    if (e > 0.0f){
      atomicAdd(&deg[s], 1);
      atomicAdd(&deg[d], 1);
      int hi = s > d ? s : d;
      int lo = s > d ? d : s;
      atomicMin(&Lg[hi], lo);           // CC round 1: zero reads
    }
  }
  bool c = (!selfe) && (e > 0.0f);
  unsigned long long m = __ballot(c);
  if (m){
    int lane = threadIdx.x & 63;
    int leader = __ffsll((unsigned long long)m) - 1;
    int base = 0;
    if (lane == leader) base = atomicAdd(np, __popcll(m));
    base = __shfl(base, leader);
    if (c){
      int prefix = __popcll(m & ((1ull << lane) - 1ull));
      pairs[base + prefix] = ((unsigned int)s << 13) | (unsigned int)d;
    }
  }
}

// flatten: pointer-jump every node to its label fixpoint (labels <= index,
// strictly decreasing along chains -> terminates; concurrent shortcuts benign)
__global__ void k_flat(int* __restrict__ Lg){
  int i = blockIdx.x * blockDim.x + threadIdx.x;
  if (i >= N_NODES) return;
  int l = Lg[i];
  while (true){ int q = Lg[l]; if (q == l) break; l = q; }
  Lg[i] = l;
}

// guarded relax over pairs: most pairs already have equal labels (skip);
// otherwise one atomicMin on the larger endpoint. Monotone-safe.
__global__ void k_relax(const unsigned int* __restrict__ pairs,
                        const int* __restrict__ np, int* __restrict__ Lg){
  int n = *np;
  int k = blockIdx.x * blockDim.x + threadIdx.x;
  int stride = gridDim.x * blockDim.x;
  for (; k < n; k += stride){
    unsigned int p = pairs[k];
    int s = (int)(p >> 13), d = (int)(p & 8191u);
    int a = Lg[s], b = Lg[d];
    if (a < b)      atomicMin(&Lg[d], a);
    else if (b < a) atomicMin(&Lg[s], b);
  }
}

// single-block finisher: LDS labels, filter actives from pairs stream,
// exact fixpoint on residual, rank roots, emit cluster/new_batch.
__global__ void __launch_bounds__(1024) k_rank1(
    const unsigned int* __restrict__ pairs, const int* __restrict__ np,
    const int* __restrict__ Lg, const int* __restrict__ batch,
    int* __restrict__ cluster_i, float* __restrict__ out_cluster,
    float* __restrict__ out_batch){
  __shared__ int L[N_NODES];            // 32 KB
  __shared__ int wsum[1024];            // 4 KB
  __shared__ unsigned int act[ACT_CAP]; // 96 KB
  __shared__ int nact, flag;
  int t = threadIdx.x;

  for (int i = t; i < N_NODES; i += 1024) L[i] = Lg[i];
  for (int i = t; i < N_NODES; i += 1024) out_batch[i] = 0.0f;
  if (t == 0){ nact = 0; flag = 0; }
  __syncthreads();

  int n = *np;
  // filter still-active pairs into LDS (read-only on L here)
  for (int k = t; k < n; k += 1024){
    unsigned int p = pairs[k];
    int s = (int)(p >> 13), d = (int)(p & 8191u);
    if (L[s] != L[d]){
      int a = atomicAdd(&nact, 1);
      if (a < ACT_CAP) act[a] = p;
    }
  }
  __syncthreads();
  int na = nact;
  if (na > 0){
    bool inlds = (na <= ACT_CAP);
    int mend = inlds ? na : n;          // overflow fallback: re-stream all pairs
    while (true){
      if (t == 0) flag = 0;
      __syncthreads();
      for (int k = t; k < mend; k += 1024){
        unsigned int p = inlds ? act[k] : pairs[k];
        int s = (int)(p >> 13), d = (int)(p & 8191u);
        int a = L[s], b = L[d];
        if (a == b) continue;
        int m = a < b ? a : b;
        atomicMin(&L[s], m);
        atomicMin(&L[d], m);
        if (a > m) atomicMin(&L[a], m);
        else       atomicMin(&L[b], m);
        flag = 1;
      }
      __syncthreads();
      if (!flag) break;
      for (int i = t; i < N_NODES; i += 1024){
        int l = L[i];
        while (true){ int q = L[l]; if (q == l) break; l = q; }
        L[i] = l;
      }
      __syncthreads();
    }
  }

  // L[i] == min node index of i's component (flattened)
  int base = t * 8;
  int l_reg[8];
  #pragma unroll
  for (int j = 0; j < 8; ++j) l_reg[j] = L[base + j];
  __syncthreads();

  // rank roots: flag + block-wide scan
  int f[8]; int s = 0;
  #pragma unroll
  for (int j = 0; j < 8; ++j){ f[j] = (l_reg[j] == base + j) ? 1 : 0; s += f[j]; }
  wsum[t] = s;
  __syncthreads();
  for (int off = 1; off < 1024; off <<= 1){
    int v = (t >= off) ? wsum[t - off] : 0;
    __syncthreads();
    wsum[t] += v;
    __syncthreads();
  }
  int run = wsum[t] - s;                // exclusive prefix
  #pragma unroll
  for (int j = 0; j < 8; ++j){
    run += f[j];
    if (f[j]) L[base + j] = run - 1;    // root slot <- cluster id
  }
  __syncthreads();

  #pragma unroll
  for (int j = 0; j < 8; ++j){
    int i = base + j;
    int c = L[l_reg[j]];
    cluster_i[i] = c;
    out_cluster[i] = (float)c;
    out_batch[c] = (float)batch[i];     // last-write-wins; batch uniform (0)
  }
}

// FUSED: blocks 0..255 compute y rows on the fly and RLE-accumulate into
// X_new (32 nodes/block); blocks 256.. nontemporal-zero A_c (268 MB).
// Disjoint output regions; X_new was zeroed in k_start.
__global__ void k_yx(const float* __restrict__ x, const uint2* __restrict__ edata,
                     const int* __restrict__ cnt, const int* __restrict__ deg,
                     const int* __restrict__ cluster_i, float* __restrict__ Xn,
                     u32x4* __restrict__ ac4, long long na4){
  int t = threadIdx.x;                  // 256 threads = feature dim
  if (blockIdx.x >= 256){
    long long i = (long long)(blockIdx.x - 256) * blockDim.x + t;
    long long stride = (long long)(gridDim.x - 256) * blockDim.x;
    u32x4 z = (u32x4)(0u);
    for (; i < na4; i += stride) __builtin_nontemporal_store(z, &ac4[i]);
    return;
  }
  int node0 = blockIdx.x * 32;
  float acc = 0.0f;
  int cur = cluster_i[node0];
  for (int j = 0; j < 32; ++j){
    int i = node0 + j;
    int c = cluster_i[i];
    if (c != cur){
      atomicAdd(&Xn[(size_t)cur * N_FEAT + t], acc);
      acc = 0.0f; cur = c;
    }
    float yv = (deg[i] == 0) ? x[(size_t)i * N_FEAT + t] : 0.0f;
    int m = cnt[i];
    const uint2* row = edata + (size_t)i * MAXDEG;
    for (int j2 = 0; j2 < m; ++j2){
      uint2 v = row[j2];
      yv += __uint_as_float(v.y) * x[(size_t)v.x * N_FEAT + t];
    }
    acc += yv;
  }
  atomicAdd(&Xn[(size_t)cur * N_FEAT + t], acc);
}

// A_c[cs,cd] += 1 per directed non-self edge crossing clusters (diag zeroed by ref)
__global__ void k_ac(const int* __restrict__ ei, const int* __restrict__ cluster_i,
                     float* __restrict__ Ac){
  int k = blockIdx.x * blockDim.x + threadIdx.x;
  if (k >= N_DIR) return;
  int s, d; edge_sd(ei, k, s, d);
  if (s == d) return;
  int cs = cluster_i[s], cd = cluster_i[d];
  if (cs != cd) atomicAdd(&Ac[(size_t)cs * N_NODES + cd], 1.0f);
}

// ---------- launcher ----------

extern "C" void kernel_launch(void* const* d_in, const int* in_sizes, int n_in,
                              void* d_out, int out_size, void* d_ws, size_t ws_size,
                              hipStream_t stream){
  const float* x     = (const float*)d_in[0];
  const int*   ei    = (const int*)  d_in[1];
  const int*   batch = (const int*)  d_in[2];
  const float* lw    = (const float*)d_in[3];
  const float* lb    = (const float*)d_in[4];

  float* out = (float*)d_out;
  float* Xn  = out;                                       // 8192*256
  float* Ac  = Xn + (size_t)N_NODES * N_FEAT;             // 8192*8192
  float* ob  = Ac + (size_t)N_NODES * N_NODES;            // 8192 (new_batch)
  float* oc  = ob + N_NODES;                              // 8192 (cluster)

  char* w = (char*)d_ws;
  float* p1        = (float*)w; w += (size_t)N_NODES * 4;
  float* p2        = (float*)w; w += (size_t)N_NODES * 4;
  int*   cluster_i = (int*)  w; w += (size_t)N_NODES * 4;
  int*   Lg        = (int*)  w; w += (size_t)N_NODES * 4;
  // contiguous meta block: cnt | deg | np  (zeroed by k_start)
  int*   meta      = (int*)  w;
  int*   cnt       = meta;
  int*   deg       = meta + N_NODES;
  int*   np        = meta + 2 * N_NODES;
  int    nmeta     = 2 * N_NODES + 16;
  w += (size_t)nmeta * 4;
  unsigned int* pairs = (unsigned int*)w; w += (size_t)N_DIR * 4;
  uint2* edata     = (uint2*)w; w += (size_t)N_NODES * MAXDEG * 8;

  int nx4 = (N_NODES * N_FEAT) / 4;                       // X_new in uint4
  long long na4 = ((long long)N_NODES * N_NODES) / 4;     // A_c in uint4

  k_start <<<2048, 256, 0, stream>>>(meta, nmeta, Lg, (u32x4*)Xn, nx4);
  k_proj  <<<N_NODES, 256, 0, stream>>>(x, lw, p1, p2);
  k_edges <<<N_DIR / 256, 256, 0, stream>>>(ei, p1, p2, lb, cnt, deg, Lg,
                                            edata, pairs, np);
  k_flat  <<<N_NODES / 256, 256, 0, stream>>>(Lg);
  k_relax <<<512, 256, 0, stream>>>(pairs, np, Lg);
  k_flat  <<<N_NODES / 256, 256, 0, stream>>>(Lg);
  k_rank1 <<<1, 1024, 0, stream>>>(pairs, np, Lg, batch, cluster_i, oc, ob);
  k_yx    <<<256 + 1024, 256, 0, stream>>>(x, edata, cnt, deg, cluster_i, Xn,
                                           (u32x4*)Ac, na4);
  k_ac    <<<N_DIR / 256, 256, 0, stream>>>(ei, cluster_i, Ac);
}

// Round 16
// 322.133 us; speedup vs baseline: 1.5648x; 1.5648x over previous
//
#include <hip/hip_runtime.h>
#include <math.h>

#define N_NODES 8192
#define N_FEAT  256
#define N_EDGES 131072
#define N_DIR   (2*N_EDGES)
#define MAXDEG  128    // slot-table width; in-degree is Poisson(32), P(>=128)~0
#define ACT_CAP 24576  // LDS capacity for residual active pairs
#define ZBLK    2048   // zero-phase blocks inside k_big

typedef unsigned int u32x4 __attribute__((ext_vector_type(4)));

// ---------- helpers ----------

// directed edge k: s = ei[k]; d = ei[k<E ? k+E : k-E]
__device__ __forceinline__ void edge_sd(const int* __restrict__ ei, int k, int& s, int& d){
  s = ei[k];
  d = (k < N_EDGES) ? ei[k + N_EDGES] : ei[k - N_EDGES];
}

// ---------- kernels ----------

// init meta (cnt|deg|np -> 0), Lg = identity, and zero X_new (8 MB)
__global__ void k_start(int* __restrict__ meta, int nmeta, int* __restrict__ Lg,
                        u32x4* __restrict__ xn4, int nx4){
  int i = blockIdx.x * blockDim.x + threadIdx.x;
  if (i < nmeta) meta[i] = 0;
  if (i < N_NODES) Lg[i] = i;
  u32x4 z = (u32x4)(0u);
  int stride = gridDim.x * blockDim.x;
  for (int k = i; k < nx4; k += stride) __builtin_nontemporal_store(z, &xn4[k]);
}

// p1[i] = dot(x[i], w[:256]); p2[i] = dot(x[i], w[256:])  (f64 accumulate)
__global__ void k_proj(const float* __restrict__ x, const float* __restrict__ w,
                       float* __restrict__ p1, float* __restrict__ p2){
  int i = blockIdx.x;
  int t = threadIdx.x;                  // 256 threads
  float v = x[(size_t)i * N_FEAT + t];
  double a = (double)v * (double)w[t];
  double b = (double)v * (double)w[N_FEAT + t];
  for (int off = 32; off; off >>= 1){
    a += __shfl_down(a, off);
    b += __shfl_down(b, off);
  }
  __shared__ double sa[4], sb[4];
  int wid = t >> 6, lane = t & 63;
  if (lane == 0){ sa[wid] = a; sb[wid] = b; }
  __syncthreads();
  if (t == 0){
    p1[i] = (float)(sa[0] + sa[1] + sa[2] + sa[3]);
    p2[i] = (float)(sb[0] + sb[1] + sb[2] + sb[3]);
  }
}

// e per directed edge; (src,e) slot record by destination; contract degree;
// compacted contract pairs; free CC round 1 (Lg==identity -> atomicMin(hi,lo))
__global__ void k_edges(const int* __restrict__ ei, const float* __restrict__ p1,
                        const float* __restrict__ p2, const float* __restrict__ lb,
                        int* __restrict__ cnt, int* __restrict__ deg,
                        int* __restrict__ Lg, uint2* __restrict__ edata,
                        unsigned int* __restrict__ pairs, int* __restrict__ np){
  int k = blockIdx.x * blockDim.x + threadIdx.x;
  int s, d; edge_sd(ei, k, s, d);
  bool selfe = (s == d);
  float e = 0.0f;
  if (!selfe){
    float z = p1[s] + p2[d] + lb[0];
    e = tanhf(z);
    int slot = atomicAdd(&cnt[d], 1);
    uint2 v; v.x = (unsigned int)s; v.y = __float_as_uint(e);
    edata[(size_t)d * MAXDEG + slot] = v;
    if (e > 0.0f){
      atomicAdd(&deg[s], 1);
      atomicAdd(&deg[d], 1);
      int hi = s > d ? s : d;
      int lo = s > d ? d : s;
      atomicMin(&Lg[hi], lo);           // CC round 1: zero reads
    }
  }
  bool c = (!selfe) && (e > 0.0f);
  unsigned long long m = __ballot(c);
  if (m){
    int lane = threadIdx.x & 63;
    int leader = __ffsll((unsigned long long)m) - 1;
    int base = 0;
    if (lane == leader) base = atomicAdd(np, __popcll(m));
    base = __shfl(base, leader);
    if (c){
      int prefix = __popcll(m & ((1ull << lane) - 1ull));
      pairs[base + prefix] = ((unsigned int)s << 13) | (unsigned int)d;
    }
  }
}

// flatten: pointer-jump every node to its label fixpoint (labels <= index,
// strictly decreasing along chains -> terminates; concurrent shortcuts benign)
__global__ void k_flat(int* __restrict__ Lg){
  int i = blockIdx.x * blockDim.x + threadIdx.x;
  if (i >= N_NODES) return;
  int l = Lg[i];
  while (true){ int q = Lg[l]; if (q == l) break; l = q; }
  Lg[i] = l;
}

// guarded relax over pairs: most pairs already have equal labels (skip);
// otherwise one atomicMin on the larger endpoint. Monotone-safe.
__global__ void k_relax(const unsigned int* __restrict__ pairs,
                        const int* __restrict__ np, int* __restrict__ Lg){
  int n = *np;
  int k = blockIdx.x * blockDim.x + threadIdx.x;
  int stride = gridDim.x * blockDim.x;
  for (; k < n; k += stride){
    unsigned int p = pairs[k];
    int s = (int)(p >> 13), d = (int)(p & 8191u);
    int a = Lg[s], b = Lg[d];
    if (a < b)      atomicMin(&Lg[d], a);
    else if (b < a) atomicMin(&Lg[s], b);
  }
}

// single-block finisher: LDS labels, filter actives from pairs stream,
// exact fixpoint on residual, rank roots, emit cluster/new_batch.
__global__ void __launch_bounds__(1024) k_rank1(
    const unsigned int* __restrict__ pairs, const int* __restrict__ np,
    const int* __restrict__ Lg, const int* __restrict__ batch,
    int* __restrict__ cluster_i, float* __restrict__ out_cluster,
    float* __restrict__ out_batch){
  __shared__ int L[N_NODES];            // 32 KB
  __shared__ int wsum[1024];            // 4 KB
  __shared__ unsigned int act[ACT_CAP]; // 96 KB
  __shared__ int nact, flag;
  int t = threadIdx.x;

  for (int i = t; i < N_NODES; i += 1024) L[i] = Lg[i];
  for (int i = t; i < N_NODES; i += 1024) out_batch[i] = 0.0f;
  if (t == 0){ nact = 0; flag = 0; }
  __syncthreads();

  int n = *np;
  // filter still-active pairs into LDS (read-only on L here)
  for (int k = t; k < n; k += 1024){
    unsigned int p = pairs[k];
    int s = (int)(p >> 13), d = (int)(p & 8191u);
    if (L[s] != L[d]){
      int a = atomicAdd(&nact, 1);
      if (a < ACT_CAP) act[a] = p;
    }
  }
  __syncthreads();
  int na = nact;
  if (na > 0){
    bool inlds = (na <= ACT_CAP);
    int mend = inlds ? na : n;          // overflow fallback: re-stream all pairs
    while (true){
      if (t == 0) flag = 0;
      __syncthreads();
      for (int k = t; k < mend; k += 1024){
        unsigned int p = inlds ? act[k] : pairs[k];
        int s = (int)(p >> 13), d = (int)(p & 8191u);
        int a = L[s], b = L[d];
        if (a == b) continue;
        int m = a < b ? a : b;
        atomicMin(&L[s], m);
        atomicMin(&L[d], m);
        if (a > m) atomicMin(&L[a], m);
        else       atomicMin(&L[b], m);
        flag = 1;
      }
      __syncthreads();
      if (!flag) break;
      for (int i = t; i < N_NODES; i += 1024){
        int l = L[i];
        while (true){ int q = L[l]; if (q == l) break; l = q; }
        L[i] = l;
      }
      __syncthreads();
    }
  }

  // L[i] == min node index of i's component (flattened)
  int base = t * 8;
  int l_reg[8];
  #pragma unroll
  for (int j = 0; j < 8; ++j) l_reg[j] = L[base + j];
  __syncthreads();

  // rank roots: flag + block-wide scan
  int f[8]; int s = 0;
  #pragma unroll
  for (int j = 0; j < 8; ++j){ f[j] = (l_reg[j] == base + j) ? 1 : 0; s += f[j]; }
  wsum[t] = s;
  __syncthreads();
  for (int off = 1; off < 1024; off <<= 1){
    int v = (t >= off) ? wsum[t - off] : 0;
    __syncthreads();
    wsum[t] += v;
    __syncthreads();
  }
  int run = wsum[t] - s;                // exclusive prefix
  #pragma unroll
  for (int j = 0; j < 8; ++j){
    run += f[j];
    if (f[j]) L[base + j] = run - 1;    // root slot <- cluster id
  }
  __syncthreads();

  #pragma unroll
  for (int j = 0; j < 8; ++j){
    int i = base + j;
    int c = L[l_reg[j]];
    cluster_i[i] = c;
    out_cluster[i] = (float)c;
    out_batch[c] = (float)batch[i];     // last-write-wins; batch uniform (0)
  }
}

// OVERLAP: blocks 0..8191 = y-gather at native geometry (one node per block,
// 256 threads = feature dim, L3-read-bound); blocks 8192.. = nontemporal
// zero of A_c (268 MB, HBM-write-bound). Disjoint outputs, complementary
// resources.
__global__ void k_big(const float* __restrict__ x, const uint2* __restrict__ edata,
                      const int* __restrict__ cnt, const int* __restrict__ deg,
                      float* __restrict__ y,
                      u32x4* __restrict__ ac4, long long na4){
  int t = threadIdx.x;
  if (blockIdx.x >= N_NODES){
    long long i = (long long)(blockIdx.x - N_NODES) * blockDim.x + t;
    long long stride = (long long)ZBLK * blockDim.x;
    u32x4 z = (u32x4)(0u);
    for (; i < na4; i += stride) __builtin_nontemporal_store(z, &ac4[i]);
    return;
  }
  int i = blockIdx.x;
  int m = cnt[i];
  float acc = (deg[i] == 0) ? x[(size_t)i * N_FEAT + t] : 0.0f;
  const uint2* row = edata + (size_t)i * MAXDEG;
  for (int j = 0; j < m; ++j){
    uint2 v = row[j];
    acc += __uint_as_float(v.y) * x[(size_t)v.x * N_FEAT + t];
  }
  y[(size_t)i * N_FEAT + t] = acc;
}

// X_new[cluster[i],:] += y[i,:]  (run-length register accumulation, then atomicAdd)
__global__ void k_xnew(const float* __restrict__ y, const int* __restrict__ cluster_i,
                       float* __restrict__ Xn){
  int t = threadIdx.x;                  // 256 threads
  int node0 = blockIdx.x * 32;
  float acc = 0.0f;
  int cur = cluster_i[node0];
  for (int j = 0; j < 32; ++j){
    int node = node0 + j;
    int c = cluster_i[node];
    if (c != cur){
      atomicAdd(&Xn[(size_t)cur * N_FEAT + t], acc);
      acc = 0.0f; cur = c;
    }
    acc += y[(size_t)node * N_FEAT + t];
  }
  atomicAdd(&Xn[(size_t)cur * N_FEAT + t], acc);
}

// A_c[cs,cd] += 1 per directed non-self edge crossing clusters (diag zeroed by ref)
__global__ void k_ac(const int* __restrict__ ei, const int* __restrict__ cluster_i,
                     float* __restrict__ Ac){
  int k = blockIdx.x * blockDim.x + threadIdx.x;
  if (k >= N_DIR) return;
  int s, d; edge_sd(ei, k, s, d);
  if (s == d) return;
  int cs = cluster_i[s], cd = cluster_i[d];
  if (cs != cd) atomicAdd(&Ac[(size_t)cs * N_NODES + cd], 1.0f);
}

// ---------- launcher ----------

extern "C" void kernel_launch(void* const* d_in, const int* in_sizes, int n_in,
                              void* d_out, int out_size, void* d_ws, size_t ws_size,
                              hipStream_t stream){
  const float* x     = (const float*)d_in[0];
  const int*   ei    = (const int*)  d_in[1];
  const int*   batch = (const int*)  d_in[2];
  const float* lw    = (const float*)d_in[3];
  const float* lb    = (const float*)d_in[4];

  float* out = (float*)d_out;
  float* Xn  = out;                                       // 8192*256
  float* Ac  = Xn + (size_t)N_NODES * N_FEAT;             // 8192*8192
  float* ob  = Ac + (size_t)N_NODES * N_NODES;            // 8192 (new_batch)
  float* oc  = ob + N_NODES;                              // 8192 (cluster)

  char* w = (char*)d_ws;
  float* p1        = (float*)w; w += (size_t)N_NODES * 4;
  float* p2        = (float*)w; w += (size_t)N_NODES * 4;
  int*   cluster_i = (int*)  w; w += (size_t)N_NODES * 4;
  int*   Lg        = (int*)  w; w += (size_t)N_NODES * 4;
  // contiguous meta block: cnt | deg | np  (zeroed by k_start)
  int*   meta      = (int*)  w;
  int*   cnt       = meta;
  int*   deg       = meta + N_NODES;
  int*   np        = meta + 2 * N_NODES;
  int    nmeta     = 2 * N_NODES + 16;
  w += (size_t)nmeta * 4;
  unsigned int* pairs = (unsigned int*)w; w += (size_t)N_DIR * 4;
  uint2* edata     = (uint2*)w; w += (size_t)N_NODES * MAXDEG * 8;
  float* y         = (float*)w; w += (size_t)N_NODES * N_FEAT * 4;

  int nx4 = (N_NODES * N_FEAT) / 4;                       // X_new in uint4
  long long na4 = ((long long)N_NODES * N_NODES) / 4;     // A_c in uint4

  k_start <<<2048, 256, 0, stream>>>(meta, nmeta, Lg, (u32x4*)Xn, nx4);
  k_proj  <<<N_NODES, 256, 0, stream>>>(x, lw, p1, p2);
  k_edges <<<N_DIR / 256, 256, 0, stream>>>(ei, p1, p2, lb, cnt, deg, Lg,
                                            edata, pairs, np);
  k_flat  <<<N_NODES / 256, 256, 0, stream>>>(Lg);
  k_relax <<<512, 256, 0, stream>>>(pairs, np, Lg);
  k_flat  <<<N_NODES / 256, 256, 0, stream>>>(Lg);
  k_rank1 <<<1, 1024, 0, stream>>>(pairs, np, Lg, batch, cluster_i, oc, ob);
  k_big   <<<N_NODES + ZBLK, 256, 0, stream>>>(x, edata, cnt, deg, y,
                                               (u32x4*)Ac, na4);
  k_xnew  <<<N_NODES / 32, 256, 0, stream>>>(y, cluster_i, Xn);
  k_ac    <<<N_DIR / 256, 256, 0, stream>>>(ei, cluster_i, Ac);
}

// Round 17
// 291.452 us; speedup vs baseline: 1.7296x; 1.1053x over previous
//
#include <hip/hip_runtime.h>
#include <math.h>

#define N_NODES 8192
#define N_FEAT  256
#define N_EDGES 131072
#define N_DIR   (2*N_EDGES)
#define MAXDEG  128    // slot-table width; degrees are Poisson(~32), P(>=128)~0
#define ACT_CAP 24576  // LDS capacity for residual active pairs

typedef unsigned int u32x4 __attribute__((ext_vector_type(4)));

// ---------- helpers ----------

// directed edge k: s = ei[k]; d = ei[k<E ? k+E : k-E]
__device__ __forceinline__ void edge_sd(const int* __restrict__ ei, int k, int& s, int& d){
  s = ei[k];
  d = (k < N_EDGES) ? ei[k + N_EDGES] : ei[k - N_EDGES];
}

// round-to-nearest-even float -> bf16 bits
__device__ __forceinline__ unsigned short f2bf(float f){
  unsigned int u = __float_as_uint(f);
  unsigned int r = u + 0x7FFFu + ((u >> 16) & 1u);
  return (unsigned short)(r >> 16);
}

// ---------- kernels ----------

// init meta (cnt|deg|ncnt|np|ngact -> 0) and label buffer La = identity
__global__ void k_start(int* __restrict__ meta, int nmeta, int* __restrict__ La){
  int i = blockIdx.x * blockDim.x + threadIdx.x;
  if (i < nmeta) meta[i] = 0;
  if (i < N_NODES) La[i] = i;
}

// p1[i] = dot(x[i], w[:256]); p2[i] = dot(x[i], w[256:])  (f64 accumulate)
// + emit bf16 copy of x (halves k_y's gather traffic)
__global__ void k_proj(const float* __restrict__ x, const float* __restrict__ w,
                       float* __restrict__ p1, float* __restrict__ p2,
                       unsigned short* __restrict__ xb){
  int i = blockIdx.x;
  int t = threadIdx.x;                  // 256 threads
  float v = x[(size_t)i * N_FEAT + t];
  xb[(size_t)i * N_FEAT + t] = f2bf(v);
  double a = (double)v * (double)w[t];
  double b = (double)v * (double)w[N_FEAT + t];
  for (int off = 32; off; off >>= 1){
    a += __shfl_down(a, off);
    b += __shfl_down(b, off);
  }
  __shared__ double sa[4], sb[4];
  int wid = t >> 6, lane = t & 63;
  if (lane == 0){ sa[wid] = a; sb[wid] = b; }
  __syncthreads();
  if (t == 0){
    p1[i] = (float)(sa[0] + sa[1] + sa[2] + sa[3]);
    p2[i] = (float)(sb[0] + sb[1] + sb[2] + sb[3]);
  }
}

// e per directed edge; (src,e) slot record by destination; contract degree;
// undirected contract adjacency (nbr/ncnt); compacted contract pairs.
__global__ void k_edges(const int* __restrict__ ei, const float* __restrict__ p1,
                        const float* __restrict__ p2, const float* __restrict__ lb,
                        int* __restrict__ cnt, int* __restrict__ deg,
                        int* __restrict__ ncnt, int* __restrict__ nbr,
                        uint2* __restrict__ edata,
                        unsigned int* __restrict__ pairs, int* __restrict__ np){
  int k = blockIdx.x * blockDim.x + threadIdx.x;
  int s, d; edge_sd(ei, k, s, d);
  bool selfe = (s == d);
  float e = 0.0f;
  if (!selfe){
    float z = p1[s] + p2[d] + lb[0];
    e = tanhf(z);
    int slot = atomicAdd(&cnt[d], 1);
    uint2 v; v.x = (unsigned int)s; v.y = __float_as_uint(e);
    edata[(size_t)d * MAXDEG + slot] = v;
    if (e > 0.0f){
      atomicAdd(&deg[s], 1);
      atomicAdd(&deg[d], 1);
      int a = atomicAdd(&ncnt[s], 1);
      nbr[(size_t)s * MAXDEG + a] = d;
      int b = atomicAdd(&ncnt[d], 1);
      nbr[(size_t)d * MAXDEG + b] = s;
    }
  }
  bool c = (!selfe) && (e > 0.0f);
  unsigned long long m = __ballot(c);
  if (m){
    int lane = threadIdx.x & 63;
    int leader = __ffsll((unsigned long long)m) - 1;
    int base = 0;
    if (lane == leader) base = atomicAdd(np, __popcll(m));
    base = __shfl(base, leader);
    if (c){
      int prefix = __popcll(m & ((1ull << lane) - 1ull));
      pairs[base + prefix] = ((unsigned int)s << 13) | (unsigned int)d;
    }
  }
}

// Jacobi min-label pass: Lout[i] = min(Lin[i], min_j Lin[nbr[i][j]]).
// Lin is READ-ONLY; Lout is a different buffer, plain coalesced store.
__global__ void k_jac(const int* __restrict__ Lin, int* __restrict__ Lout,
                      const int* __restrict__ ncnt, const int* __restrict__ nbr){
  int i = blockIdx.x * blockDim.x + threadIdx.x;
  if (i >= N_NODES) return;
  int m = Lin[i];
  int c = ncnt[i];
  const int* row = nbr + (size_t)i * MAXDEG;
  for (int j = 0; j < c; ++j){
    int l = Lin[row[j]];
    m = l < m ? l : m;
  }
  Lout[i] = m;
}

// flatten: pointer-jump every node to its label fixpoint (labels <= index,
// strictly decreasing along chains -> terminates; concurrent shortcuts benign)
__global__ void k_flat(int* __restrict__ Lg){
  int i = blockIdx.x * blockDim.x + threadIdx.x;
  if (i >= N_NODES) return;
  int l = Lg[i];
  while (true){ int q = Lg[l]; if (q == l) break; l = q; }
  Lg[i] = l;
}

// compact still-active pairs (distinct labels) on the quiescent state
__global__ void k_collect(const unsigned int* __restrict__ pairs,
                          const int* __restrict__ np, const int* __restrict__ Lg,
                          unsigned int* __restrict__ gact, int* __restrict__ ngact){
  int n = *np;
  int k = blockIdx.x * blockDim.x + threadIdx.x;
  int stride = gridDim.x * blockDim.x;
  for (; k < n; k += stride){
    unsigned int p = pairs[k];
    int s = (int)(p >> 13), d = (int)(p & 8191u);
    bool act = (Lg[s] != Lg[d]);
    unsigned long long m = __ballot(act);
    if (m){
      int lane = threadIdx.x & 63;
      int leader = __ffsll((unsigned long long)m) - 1;
      int base = 0;
      if (lane == leader) base = atomicAdd(ngact, __popcll(m));
      base = __shfl(base, leader);
      if (act){
        int prefix = __popcll(m & ((1ull << lane) - 1ull));
        gact[base + prefix] = p;
      }
    }
  }
}

// FUSED: block 0 = exact CC fixpoint on residual actives (LDS) + rank + emit;
// blocks 1.. = nontemporal-zero X_new and A_c.
__global__ void __launch_bounds__(1024) k_fused(
    const unsigned int* __restrict__ gact, const int* __restrict__ ngact,
    const int* __restrict__ Lg, const int* __restrict__ batch,
    int* __restrict__ cluster_i, float* __restrict__ out_cluster,
    float* __restrict__ out_batch,
    u32x4* __restrict__ zbase, long long n4){
  int t = threadIdx.x;

  if (blockIdx.x != 0){
    long long i = (long long)(blockIdx.x - 1) * blockDim.x + t;
    long long stride = (long long)(gridDim.x - 1) * blockDim.x;
    u32x4 z = (u32x4)(0u);
    for (; i < n4; i += stride) __builtin_nontemporal_store(z, &zbase[i]);
    return;
  }

  // ---- block 0 ----
  __shared__ int L[N_NODES];            // 32 KB (labels)
  __shared__ int wsum[1024];            // 4 KB scan buffer
  __shared__ unsigned int act[ACT_CAP]; // 96 KB residual pairs
  __shared__ int flag;

  for (int i = t; i < N_NODES; i += 1024) L[i] = Lg[i];
  for (int i = t; i < N_NODES; i += 1024) out_batch[i] = 0.0f;
  __syncthreads();

  int na = *ngact;
  if (na > 0){
    bool inlds = (na <= ACT_CAP);
    if (inlds){
      for (int k = t; k < na; k += 1024) act[k] = gact[k];
    }
    __syncthreads();
    while (true){
      if (t == 0) flag = 0;
      __syncthreads();
      for (int k = t; k < na; k += 1024){
        unsigned int p = inlds ? act[k] : gact[k];
        int s = (int)(p >> 13), d = (int)(p & 8191u);
        int a = L[s], b = L[d];
        if (a == b) continue;
        int m = a < b ? a : b;
        atomicMin(&L[s], m);
        atomicMin(&L[d], m);
        if (a > m) atomicMin(&L[a], m);
        else       atomicMin(&L[b], m);
        flag = 1;
      }
      __syncthreads();
      if (!flag) break;
      for (int i = t; i < N_NODES; i += 1024){
        int l = L[i];
        while (true){ int q = L[l]; if (q == l) break; l = q; }
        L[i] = l;
      }
      __syncthreads();
    }
  }

  // L[i] == min node index of i's component (flattened)
  int base = t * 8;
  int l_reg[8];
  #pragma unroll
  for (int j = 0; j < 8; ++j) l_reg[j] = L[base + j];
  __syncthreads();

  // rank roots: flag + block-wide scan (1024 threads x 8)
  int f[8]; int s = 0;
  #pragma unroll
  for (int j = 0; j < 8; ++j){ f[j] = (l_reg[j] == base + j) ? 1 : 0; s += f[j]; }
  wsum[t] = s;
  __syncthreads();
  for (int off = 1; off < 1024; off <<= 1){
    int v = (t >= off) ? wsum[t - off] : 0;
    __syncthreads();
    wsum[t] += v;
    __syncthreads();
  }
  int run = wsum[t] - s;                // exclusive prefix
  #pragma unroll
  for (int j = 0; j < 8; ++j){
    run += f[j];
    if (f[j]) L[base + j] = run - 1;    // root slot <- cluster id
  }
  __syncthreads();

  #pragma unroll
  for (int j = 0; j < 8; ++j){
    int i = base + j;
    int c = L[l_reg[j]];
    cluster_i[i] = c;
    out_cluster[i] = (float)c;
    out_batch[c] = (float)batch[i];     // last-write-wins; batch uniform (0)
  }
}

// y[i,:] = (isolated ? x[i,:] : 0) + sum_{edges s->i} e * x_bf16[s,:]
// 128 threads/node; packed uint loads (2 bf16 features per thread).
__global__ void k_y(const float* __restrict__ x, const unsigned int* __restrict__ xb2,
                    const uint2* __restrict__ edata,
                    const int* __restrict__ cnt, const int* __restrict__ deg,
                    float2* __restrict__ y2){
  int i = blockIdx.x;
  int t = threadIdx.x;                  // 0..127; features 2t, 2t+1
  int m = cnt[i];
  float2 acc;
  if (deg[i] == 0){
    acc.x = x[(size_t)i * N_FEAT + 2 * t];
    acc.y = x[(size_t)i * N_FEAT + 2 * t + 1];
  } else {
    acc.x = 0.0f; acc.y = 0.0f;
  }
  const uint2* row = edata + (size_t)i * MAXDEG;
  for (int j = 0; j < m; ++j){
    uint2 v = row[j];
    float e = __uint_as_float(v.y);
    unsigned int pk = xb2[(size_t)v.x * (N_FEAT / 2) + t];
    float xlo = __uint_as_float(pk << 16);
    float xhi = __uint_as_float(pk & 0xFFFF0000u);
    acc.x += e * xlo;
    acc.y += e * xhi;
  }
  y2[(size_t)i * (N_FEAT / 2) + t] = acc;
}

// X_new[cluster[i],:] += y[i,:]  (run-length register accumulation, then atomicAdd)
__global__ void k_xnew(const float* __restrict__ y, const int* __restrict__ cluster_i,
                       float* __restrict__ Xn){
  int t = threadIdx.x;                  // 256 threads
  int node0 = blockIdx.x * 32;
  float acc = 0.0f;
  int cur = cluster_i[node0];
  for (int j = 0; j < 32; ++j){
    int node = node0 + j;
    int c = cluster_i[node];
    if (c != cur){
      atomicAdd(&Xn[(size_t)cur * N_FEAT + t], acc);
      acc = 0.0f; cur = c;
    }
    acc += y[(size_t)node * N_FEAT + t];
  }
  atomicAdd(&Xn[(size_t)cur * N_FEAT + t], acc);
}

// A_c[cs,cd] += 1 per directed non-self edge crossing clusters (diag zeroed by ref)
__global__ void k_ac(const int* __restrict__ ei, const int* __restrict__ cluster_i,
                     float* __restrict__ Ac){
  int k = blockIdx.x * blockDim.x + threadIdx.x;
  if (k >= N_DIR) return;
  int s, d; edge_sd(ei, k, s, d);
  if (s == d) return;
  int cs = cluster_i[s], cd = cluster_i[d];
  if (cs != cd) atomicAdd(&Ac[(size_t)cs * N_NODES + cd], 1.0f);
}

// ---------- launcher ----------

extern "C" void kernel_launch(void* const* d_in, const int* in_sizes, int n_in,
                              void* d_out, int out_size, void* d_ws, size_t ws_size,
                              hipStream_t stream){
  const float* x     = (const float*)d_in[0];
  const int*   ei    = (const int*)  d_in[1];
  const int*   batch = (const int*)  d_in[2];
  const float* lw    = (const float*)d_in[3];
  const float* lb    = (const float*)d_in[4];

  float* out = (float*)d_out;
  float* Xn  = out;                                       // 8192*256
  float* Ac  = Xn + (size_t)N_NODES * N_FEAT;             // 8192*8192
  float* ob  = Ac + (size_t)N_NODES * N_NODES;            // 8192 (new_batch)
  float* oc  = ob + N_NODES;                              // 8192 (cluster)

  char* w = (char*)d_ws;
  float* p1        = (float*)w; w += (size_t)N_NODES * 4;
  float* p2        = (float*)w; w += (size_t)N_NODES * 4;
  int*   cluster_i = (int*)  w; w += (size_t)N_NODES * 4;
  int*   La        = (int*)  w; w += (size_t)N_NODES * 4;
  int*   Lb        = (int*)  w; w += (size_t)N_NODES * 4;
  // contiguous meta block: cnt | deg | ncnt | np | ngact  (zeroed by k_start)
  int*   meta      = (int*)  w;
  int*   cnt       = meta;
  int*   deg       = meta + N_NODES;
  int*   ncnt      = meta + 2 * N_NODES;
  int*   np        = meta + 3 * N_NODES;
  int*   ngact     = meta + 3 * N_NODES + 1;
  int    nmeta     = 3 * N_NODES + 16;
  w += (size_t)nmeta * 4;
  unsigned int* pairs = (unsigned int*)w; w += (size_t)N_DIR * 4;
  unsigned int* gact  = (unsigned int*)w; w += (size_t)N_DIR * 4;
  uint2* edata     = (uint2*)w; w += (size_t)N_NODES * MAXDEG * 8;
  int*   nbr       = (int*)  w; w += (size_t)N_NODES * MAXDEG * 4;
  unsigned short* xb = (unsigned short*)w; w += (size_t)N_NODES * N_FEAT * 2;
  float* y         = (float*)w; w += (size_t)N_NODES * N_FEAT * 4;

  // Xn + Ac region (ob/oc handled by fused block 0)
  long long n4 = ((long long)N_NODES * N_FEAT + (long long)N_NODES * N_NODES) / 4;

  k_start  <<<(nmeta + 255) / 256, 256, 0, stream>>>(meta, nmeta, La);
  k_proj   <<<N_NODES, 256, 0, stream>>>(x, lw, p1, p2, xb);
  k_edges  <<<N_DIR / 256, 256, 0, stream>>>(ei, p1, p2, lb, cnt, deg, ncnt, nbr,
                                             edata, pairs, np);
  k_jac    <<<N_NODES / 256, 256, 0, stream>>>(La, Lb, ncnt, nbr);
  k_flat   <<<N_NODES / 256, 256, 0, stream>>>(Lb);
  k_jac    <<<N_NODES / 256, 256, 0, stream>>>(Lb, La, ncnt, nbr);
  k_flat   <<<N_NODES / 256, 256, 0, stream>>>(La);
  k_collect<<<512, 256, 0, stream>>>(pairs, np, La, gact, ngact);
  k_fused  <<<256, 1024, 0, stream>>>(gact, ngact, La, batch, cluster_i, oc, ob,
                                      (u32x4*)out, n4);
  k_y      <<<N_NODES, 128, 0, stream>>>(x, (const unsigned int*)xb, edata,
                                         cnt, deg, (float2*)y);
  k_xnew   <<<N_NODES / 32, 256, 0, stream>>>(y, cluster_i, Xn);
  k_ac     <<<N_DIR / 256, 256, 0, stream>>>(ei, cluster_i, Ac);
}

// Round 18
// 270.875 us; speedup vs baseline: 1.8609x; 1.0760x over previous
//
#include <hip/hip_runtime.h>
#include <math.h>

#define N_NODES 8192
#define N_FEAT  256
#define N_EDGES 131072
#define N_DIR   (2*N_EDGES)
#define MAXDEG  128    // slot-table width; degrees are Poisson(~32), P(>=128)~0
#define ACT_CAP 24576  // LDS capacity for residual active pairs
#define NCL_CAP 64     // W-path capacity (input has ~1 cluster); else fallback

typedef unsigned int u32x4 __attribute__((ext_vector_type(4)));

// ---------- helpers ----------

// directed edge k: s = ei[k]; d = ei[k<E ? k+E : k-E]
__device__ __forceinline__ void edge_sd(const int* __restrict__ ei, int k, int& s, int& d){
  s = ei[k];
  d = (k < N_EDGES) ? ei[k + N_EDGES] : ei[k - N_EDGES];
}

// ---------- kernels ----------

// init meta -> 0, La = identity, W -> 0
__global__ void k_start(int* __restrict__ meta, int nmeta, int* __restrict__ La,
                        u32x4* __restrict__ w4, int nw4){
  int i = blockIdx.x * blockDim.x + threadIdx.x;
  if (i < nmeta) meta[i] = 0;
  if (i < N_NODES) La[i] = i;
  u32x4 z = (u32x4)(0u);
  int stride = gridDim.x * blockDim.x;
  for (int k = i; k < nw4; k += stride) __builtin_nontemporal_store(z, &w4[k]);
}

// p1[i] = dot(x[i], w[:256]); p2[i] = dot(x[i], w[256:])  (f64 accumulate)
__global__ void k_proj(const float* __restrict__ x, const float* __restrict__ w,
                       float* __restrict__ p1, float* __restrict__ p2){
  int i = blockIdx.x;
  int t = threadIdx.x;                  // 256 threads
  float v = x[(size_t)i * N_FEAT + t];
  double a = (double)v * (double)w[t];
  double b = (double)v * (double)w[N_FEAT + t];
  for (int off = 32; off; off >>= 1){
    a += __shfl_down(a, off);
    b += __shfl_down(b, off);
  }
  __shared__ double sa[4], sb[4];
  int wid = t >> 6, lane = t & 63;
  if (lane == 0){ sa[wid] = a; sb[wid] = b; }
  __syncthreads();
  if (t == 0){
    p1[i] = (float)(sa[0] + sa[1] + sa[2] + sa[3]);
    p2[i] = (float)(sb[0] + sb[1] + sb[2] + sb[3]);
  }
}

// e per directed edge (stored to e_val); (src,e) slot record by destination
// (fallback path); contract degree; adjacency (nbr/ncnt); compacted pairs.
__global__ void k_edges(const int* __restrict__ ei, const float* __restrict__ p1,
                        const float* __restrict__ p2, const float* __restrict__ lb,
                        int* __restrict__ cnt, int* __restrict__ deg,
                        int* __restrict__ ncnt, int* __restrict__ nbr,
                        uint2* __restrict__ edata, float* __restrict__ e_val,
                        unsigned int* __restrict__ pairs, int* __restrict__ np){
  int k = blockIdx.x * blockDim.x + threadIdx.x;
  int s, d; edge_sd(ei, k, s, d);
  bool selfe = (s == d);
  float e = 0.0f;
  if (!selfe){
    float z = p1[s] + p2[d] + lb[0];
    e = tanhf(z);
    e_val[k] = e;
    int slot = atomicAdd(&cnt[d], 1);
    uint2 v; v.x = (unsigned int)s; v.y = __float_as_uint(e);
    edata[(size_t)d * MAXDEG + slot] = v;
    if (e > 0.0f){
      atomicAdd(&deg[s], 1);
      atomicAdd(&deg[d], 1);
      int a = atomicAdd(&ncnt[s], 1);
      nbr[(size_t)s * MAXDEG + a] = d;
      int b = atomicAdd(&ncnt[d], 1);
      nbr[(size_t)d * MAXDEG + b] = s;
    }
  }
  bool c = (!selfe) && (e > 0.0f);
  unsigned long long m = __ballot(c);
  if (m){
    int lane = threadIdx.x & 63;
    int leader = __ffsll((unsigned long long)m) - 1;
    int base = 0;
    if (lane == leader) base = atomicAdd(np, __popcll(m));
    base = __shfl(base, leader);
    if (c){
      int prefix = __popcll(m & ((1ull << lane) - 1ull));
      pairs[base + prefix] = ((unsigned int)s << 13) | (unsigned int)d;
    }
  }
}

// Jacobi min-label pass: Lout[i] = min(Lin[i], min_j Lin[nbr[i][j]]).
__global__ void k_jac(const int* __restrict__ Lin, int* __restrict__ Lout,
                      const int* __restrict__ ncnt, const int* __restrict__ nbr){
  int i = blockIdx.x * blockDim.x + threadIdx.x;
  if (i >= N_NODES) return;
  int m = Lin[i];
  int c = ncnt[i];
  const int* row = nbr + (size_t)i * MAXDEG;
  for (int j = 0; j < c; ++j){
    int l = Lin[row[j]];
    m = l < m ? l : m;
  }
  Lout[i] = m;
}

// flatten: pointer-jump to label fixpoint (monotone decreasing, terminates)
__global__ void k_flat(int* __restrict__ Lg){
  int i = blockIdx.x * blockDim.x + threadIdx.x;
  if (i >= N_NODES) return;
  int l = Lg[i];
  while (true){ int q = Lg[l]; if (q == l) break; l = q; }
  Lg[i] = l;
}

// compact still-active pairs (distinct labels) on the quiescent state
__global__ void k_collect(const unsigned int* __restrict__ pairs,
                          const int* __restrict__ np, const int* __restrict__ Lg,
                          unsigned int* __restrict__ gact, int* __restrict__ ngact){
  int n = *np;
  int k = blockIdx.x * blockDim.x + threadIdx.x;
  int stride = gridDim.x * blockDim.x;
  for (; k < n; k += stride){
    unsigned int p = pairs[k];
    int s = (int)(p >> 13), d = (int)(p & 8191u);
    bool act = (Lg[s] != Lg[d]);
    unsigned long long m = __ballot(act);
    if (m){
      int lane = threadIdx.x & 63;
      int leader = __ffsll((unsigned long long)m) - 1;
      int base = 0;
      if (lane == leader) base = atomicAdd(ngact, __popcll(m));
      base = __shfl(base, leader);
      if (act){
        int prefix = __popcll(m & ((1ull << lane) - 1ull));
        gact[base + prefix] = p;
      }
    }
  }
}

// FUSED: block 0 = exact CC fixpoint on residual actives (LDS) + rank + emit
// (+ store cluster count); blocks 1.. = nontemporal-zero X_new and A_c.
__global__ void __launch_bounds__(1024) k_fused(
    const unsigned int* __restrict__ gact, const int* __restrict__ ngact,
    const int* __restrict__ Lg, const int* __restrict__ batch,
    int* __restrict__ cluster_i, float* __restrict__ out_cluster,
    float* __restrict__ out_batch, int* __restrict__ nclst,
    u32x4* __restrict__ zbase, long long n4){
  int t = threadIdx.x;

  if (blockIdx.x != 0){
    long long i = (long long)(blockIdx.x - 1) * blockDim.x + t;
    long long stride = (long long)(gridDim.x - 1) * blockDim.x;
    u32x4 z = (u32x4)(0u);
    for (; i < n4; i += stride) __builtin_nontemporal_store(z, &zbase[i]);
    return;
  }

  // ---- block 0 ----
  __shared__ int L[N_NODES];            // 32 KB (labels)
  __shared__ int wsum[1024];            // 4 KB scan buffer
  __shared__ unsigned int act[ACT_CAP]; // 96 KB residual pairs
  __shared__ int flag;

  for (int i = t; i < N_NODES; i += 1024) L[i] = Lg[i];
  for (int i = t; i < N_NODES; i += 1024) out_batch[i] = 0.0f;
  __syncthreads();

  int na = *ngact;
  if (na > 0){
    bool inlds = (na <= ACT_CAP);
    if (inlds){
      for (int k = t; k < na; k += 1024) act[k] = gact[k];
    }
    __syncthreads();
    while (true){
      if (t == 0) flag = 0;
      __syncthreads();
      for (int k = t; k < na; k += 1024){
        unsigned int p = inlds ? act[k] : gact[k];
        int s = (int)(p >> 13), d = (int)(p & 8191u);
        int a = L[s], b = L[d];
        if (a == b) continue;
        int m = a < b ? a : b;
        atomicMin(&L[s], m);
        atomicMin(&L[d], m);
        if (a > m) atomicMin(&L[a], m);
        else       atomicMin(&L[b], m);
        flag = 1;
      }
      __syncthreads();
      if (!flag) break;
      for (int i = t; i < N_NODES; i += 1024){
        int l = L[i];
        while (true){ int q = L[l]; if (q == l) break; l = q; }
        L[i] = l;
      }
      __syncthreads();
    }
  }

  // L[i] == min node index of i's component (flattened)
  int base = t * 8;
  int l_reg[8];
  #pragma unroll
  for (int j = 0; j < 8; ++j) l_reg[j] = L[base + j];
  __syncthreads();

  // rank roots: flag + block-wide scan (1024 threads x 8)
  int f[8]; int s = 0;
  #pragma unroll
  for (int j = 0; j < 8; ++j){ f[j] = (l_reg[j] == base + j) ? 1 : 0; s += f[j]; }
  wsum[t] = s;
  __syncthreads();
  for (int off = 1; off < 1024; off <<= 1){
    int v = (t >= off) ? wsum[t - off] : 0;
    __syncthreads();
    wsum[t] += v;
    __syncthreads();
  }
  int run = wsum[t] - s;                // exclusive prefix
  #pragma unroll
  for (int j = 0; j < 8; ++j){
    run += f[j];
    if (f[j]) L[base + j] = run - 1;    // root slot <- cluster id
  }
  if (t == 1023) *nclst = wsum[1023];   // total cluster count
  __syncthreads();

  #pragma unroll
  for (int j = 0; j < 8; ++j){
    int i = base + j;
    int c = L[l_reg[j]];
    cluster_i[i] = c;
    out_cluster[i] = (float)c;
    out_batch[c] = (float)batch[i];     // last-write-wins; batch uniform (0)
  }
}

// W[c][s] = sum of e over edges s->i with cluster[i]==c (+1 on isolated diag).
// Write-only scattered fp32 atomics into 2 MB — the proven-fast pattern.
__global__ void k_coeff(const int* __restrict__ ei, const float* __restrict__ e_val,
                        const int* __restrict__ cluster_i, const int* __restrict__ deg,
                        const int* __restrict__ nclst, float* __restrict__ W){
  if (*nclst > NCL_CAP) return;         // fallback path will handle
  int k = blockIdx.x * blockDim.x + threadIdx.x;
  int s, d; edge_sd(ei, k, s, d);
  if (s != d){
    float e = e_val[k];
    int c = cluster_i[d];
    atomicAdd(&W[(size_t)c * N_NODES + s], e);
  }
  if (k < N_NODES && deg[k] == 0){
    atomicAdd(&W[(size_t)cluster_i[k] * N_NODES + k], 1.0f);
  }
}

// X_new[c,:] = sum_s W[c][s] * x[s,:] — x read ONCE, coalesced; W loads are
// wave-uniform (scalar); one atomic per block per cluster.
__global__ void k_xw(const float* __restrict__ x, const float* __restrict__ W,
                     const int* __restrict__ nclst, float* __restrict__ Xn){
  int ncl = *nclst;
  if (ncl > NCL_CAP) return;            // fallback path will handle
  int t = threadIdx.x;                  // 256 threads = feature dim
  int s0 = blockIdx.x * 32;             // 256 blocks x 32 rows
  float xs[32];
  #pragma unroll
  for (int j = 0; j < 32; ++j) xs[j] = x[(size_t)(s0 + j) * N_FEAT + t];
  for (int c = 0; c < ncl; ++c){
    const float* wr = W + (size_t)c * N_NODES + s0;
    float acc = 0.0f;
    #pragma unroll
    for (int j = 0; j < 32; ++j) acc += wr[j] * xs[j];
    atomicAdd(&Xn[(size_t)c * N_FEAT + t], acc);
  }
}

// ---- fallback path (ncl > NCL_CAP): per-node gather + RLE scatter ----
__global__ void k_yfb(const float* __restrict__ x, const uint2* __restrict__ edata,
                      const int* __restrict__ cnt, const int* __restrict__ deg,
                      const int* __restrict__ nclst, float* __restrict__ y){
  if (*nclst <= NCL_CAP) return;
  int i = blockIdx.x;
  int t = threadIdx.x;
  int m = cnt[i];
  float acc = (deg[i] == 0) ? x[(size_t)i * N_FEAT + t] : 0.0f;
  const uint2* row = edata + (size_t)i * MAXDEG;
  for (int j = 0; j < m; ++j){
    uint2 v = row[j];
    acc += __uint_as_float(v.y) * x[(size_t)v.x * N_FEAT + t];
  }
  y[(size_t)i * N_FEAT + t] = acc;
}

__global__ void k_xnfb(const float* __restrict__ y, const int* __restrict__ cluster_i,
                       const int* __restrict__ nclst, float* __restrict__ Xn){
  if (*nclst <= NCL_CAP) return;
  int t = threadIdx.x;
  int node0 = blockIdx.x * 32;
  float acc = 0.0f;
  int cur = cluster_i[node0];
  for (int j = 0; j < 32; ++j){
    int node = node0 + j;
    int c = cluster_i[node];
    if (c != cur){
      atomicAdd(&Xn[(size_t)cur * N_FEAT + t], acc);
      acc = 0.0f; cur = c;
    }
    acc += y[(size_t)node * N_FEAT + t];
  }
  atomicAdd(&Xn[(size_t)cur * N_FEAT + t], acc);
}

// A_c[cs,cd] += 1 per directed non-self edge crossing clusters (diag zeroed by ref)
__global__ void k_ac(const int* __restrict__ ei, const int* __restrict__ cluster_i,
                     float* __restrict__ Ac){
  int k = blockIdx.x * blockDim.x + threadIdx.x;
  if (k >= N_DIR) return;
  int s, d; edge_sd(ei, k, s, d);
  if (s == d) return;
  int cs = cluster_i[s], cd = cluster_i[d];
  if (cs != cd) atomicAdd(&Ac[(size_t)cs * N_NODES + cd], 1.0f);
}

// ---------- launcher ----------

extern "C" void kernel_launch(void* const* d_in, const int* in_sizes, int n_in,
                              void* d_out, int out_size, void* d_ws, size_t ws_size,
                              hipStream_t stream){
  const float* x     = (const float*)d_in[0];
  const int*   ei    = (const int*)  d_in[1];
  const int*   batch = (const int*)  d_in[2];
  const float* lw    = (const float*)d_in[3];
  const float* lb    = (const float*)d_in[4];

  float* out = (float*)d_out;
  float* Xn  = out;                                       // 8192*256
  float* Ac  = Xn + (size_t)N_NODES * N_FEAT;             // 8192*8192
  float* ob  = Ac + (size_t)N_NODES * N_NODES;            // 8192 (new_batch)
  float* oc  = ob + N_NODES;                              // 8192 (cluster)

  char* w = (char*)d_ws;
  float* p1        = (float*)w; w += (size_t)N_NODES * 4;
  float* p2        = (float*)w; w += (size_t)N_NODES * 4;
  int*   cluster_i = (int*)  w; w += (size_t)N_NODES * 4;
  int*   La        = (int*)  w; w += (size_t)N_NODES * 4;
  int*   Lb        = (int*)  w; w += (size_t)N_NODES * 4;
  // contiguous meta block: cnt | deg | ncnt | np | ngact | nclst
  int*   meta      = (int*)  w;
  int*   cnt       = meta;
  int*   deg       = meta + N_NODES;
  int*   ncnt      = meta + 2 * N_NODES;
  int*   np        = meta + 3 * N_NODES;
  int*   ngact     = meta + 3 * N_NODES + 1;
  int*   nclst     = meta + 3 * N_NODES + 2;
  int    nmeta     = 3 * N_NODES + 16;
  w += (size_t)nmeta * 4;
  unsigned int* pairs = (unsigned int*)w; w += (size_t)N_DIR * 4;
  unsigned int* gact  = (unsigned int*)w; w += (size_t)N_DIR * 4;
  uint2* edata     = (uint2*)w; w += (size_t)N_NODES * MAXDEG * 8;
  int*   nbr       = (int*)  w; w += (size_t)N_NODES * MAXDEG * 4;
  float* e_val     = (float*)w; w += (size_t)N_DIR * 4;
  float* W         = (float*)w; w += (size_t)NCL_CAP * N_NODES * 4;
  float* y         = (float*)w; w += (size_t)N_NODES * N_FEAT * 4;

  // Xn + Ac region (ob/oc handled by fused block 0)
  long long n4 = ((long long)N_NODES * N_FEAT + (long long)N_NODES * N_NODES) / 4;
  int nw4 = (NCL_CAP * N_NODES) / 4;                      // W in uint4

  k_start  <<<2048, 256, 0, stream>>>(meta, nmeta, La, (u32x4*)W, nw4);
  k_proj   <<<N_NODES, 256, 0, stream>>>(x, lw, p1, p2);
  k_edges  <<<N_DIR / 256, 256, 0, stream>>>(ei, p1, p2, lb, cnt, deg, ncnt, nbr,
                                             edata, e_val, pairs, np);
  k_jac    <<<N_NODES / 256, 256, 0, stream>>>(La, Lb, ncnt, nbr);
  k_flat   <<<N_NODES / 256, 256, 0, stream>>>(Lb);
  k_jac    <<<N_NODES / 256, 256, 0, stream>>>(Lb, La, ncnt, nbr);
  k_flat   <<<N_NODES / 256, 256, 0, stream>>>(La);
  k_collect<<<512, 256, 0, stream>>>(pairs, np, La, gact, ngact);
  k_fused  <<<256, 1024, 0, stream>>>(gact, ngact, La, batch, cluster_i, oc, ob,
                                      nclst, (u32x4*)out, n4);
  k_coeff  <<<N_DIR / 256, 256, 0, stream>>>(ei, e_val, cluster_i, deg, nclst, W);
  k_xw     <<<N_NODES / 32, 256, 0, stream>>>(x, W, nclst, Xn);
  k_yfb    <<<N_NODES, 256, 0, stream>>>(x, edata, cnt, deg, nclst, y);
  k_xnfb   <<<N_NODES / 32, 256, 0, stream>>>(y, cluster_i, nclst, Xn);
  k_ac     <<<N_DIR / 256, 256, 0, stream>>>(ei, cluster_i, Ac);
}